// Round 8
// baseline (132.278 us; speedup 1.0000x reference)
//
#include <hip/hip_runtime.h>
#include <math.h>

#define N_PTS 1024
#define HID   256
#define FEAT  2048

typedef short bf16x8 __attribute__((ext_vector_type(8)));
typedef float f32x4  __attribute__((ext_vector_type(4)));

__device__ inline ushort f2bf(float f) {
    union { float f; unsigned u; } v; v.f = f;
    unsigned r = v.u + 0x7fff + ((v.u >> 16) & 1);   // round-to-nearest-even
    return (ushort)(r >> 16);
}

// ---------------- prep: weight transposes only (fp32 [K][256] -> bf16 [256][K])
// b < 128 : W1 -> W1T   128 <= b < 144 : W2 -> W2T   144 <= b < 176 : We1 -> WeT
__global__ __launch_bounds__(256) void prep(
    const float* __restrict__ W1, const float* __restrict__ W2,
    const float* __restrict__ We1, ushort* __restrict__ W1T,
    ushort* __restrict__ W2T, ushort* __restrict__ WeT)
{
    __shared__ ushort Ts[64 * 72];
    const int tid = threadIdx.x;
    int b = blockIdx.x;
    const float* src; ushort* dst; int K;
    if (b < 128)      { src = W1;  dst = W1T; K = 2048; }
    else if (b < 144) { b -= 128; src = W2;  dst = W2T; K = 256; }
    else              { b -= 144; src = We1; dst = WeT; K = 512; }
    const int k0 = (b >> 2) * 64;
    const int n0 = (b & 3) * 64;
    #pragma unroll
    for (int p = 0; p < 4; p++) {
        const int c  = p * 256 + tid;
        const int r  = c >> 4;           // k-local
        const int cq = c & 15;           // n-chunk
        float4 v = *(const float4*)&src[(size_t)(k0 + r) * 256 + n0 + cq * 4];
        Ts[(cq * 4 + 0) * 72 + r] = f2bf(v.x);
        Ts[(cq * 4 + 1) * 72 + r] = f2bf(v.y);
        Ts[(cq * 4 + 2) * 72 + r] = f2bf(v.z);
        Ts[(cq * 4 + 3) * 72 + r] = f2bf(v.w);
    }
    __syncthreads();
    #pragma unroll
    for (int p = 0; p < 2; p++) {
        const int c    = p * 256 + tid;  // 0..511
        const int row  = c >> 3;         // n-local
        const int col8 = c & 7;          // 8-wide k chunk
        *(bf16x8*)&dst[(size_t)(n0 + row) * K + k0 + col8 * 8] =
            *(bf16x8*)&Ts[row * 72 + col8 * 8];
    }
}

// ---- gemm1 v2: x1 = features @ W1T, full-K, fused colstats1 partials ------
// grid (8,64): x -> 32-col N-tile, y -> 16-row M-tile. 4 waves; wave w owns
// K-quarter [512w, 512w+512), BK=128 -> 4 iters, WAVE-PRIVATE LDS (no
// barriers in main loop). A staged directly from fp32 features (fused f2bf).
// Epilogue: cross-wave reduce (2 barriers) + plain-store x1 + statsP[y][512].
__global__ __launch_bounds__(256) void gemm1s(
    const float* __restrict__ feat, const ushort* __restrict__ B /*W1T*/,
    float* __restrict__ X /*x1*/, float* __restrict__ statsP)
{
    __shared__ __align__(16) ushort smem[26112];   // 4 x (16+32)x136
    const int tid  = threadIdx.x;
    const int lane = tid & 63;
    const int w    = tid >> 6;
    const int quad = lane >> 4, l16 = lane & 15;
    const int mBase = blockIdx.y * 16;
    const int nBase = blockIdx.x * 32;
    ushort* As = smem + w * 6528;          // [16][136]
    ushort* Bs = As + 2176;                // [32][136]

    f32x4 acc[2] = {};
    const int kw = w * 512;
    for (int it = 0; it < 4; ++it) {
        const int ks = kw + it * 128;
        #pragma unroll
        for (int p = 0; p < 4; p++) {      // A: 16x128 fp32 -> bf16
            const int c    = p * 64 + lane;
            const int row  = c >> 4;
            const int col8 = c & 15;
            const float* ap = &feat[(size_t)(mBase + row) * FEAT + ks + col8 * 8];
            float4 a0 = *(const float4*)ap;
            float4 a1 = *(const float4*)(ap + 4);
            bf16x8 o;
            o[0] = (short)f2bf(a0.x); o[1] = (short)f2bf(a0.y);
            o[2] = (short)f2bf(a0.z); o[3] = (short)f2bf(a0.w);
            o[4] = (short)f2bf(a1.x); o[5] = (short)f2bf(a1.y);
            o[6] = (short)f2bf(a1.z); o[7] = (short)f2bf(a1.w);
            *(bf16x8*)&As[row * 136 + col8 * 8] = o;
        }
        #pragma unroll
        for (int p = 0; p < 8; p++) {      // B: 32x128 bf16 copy
            const int c    = p * 64 + lane;
            const int row  = c >> 4;
            const int col8 = c & 15;
            *(bf16x8*)&Bs[row * 136 + col8 * 8] =
                *(const bf16x8*)&B[(size_t)(nBase + row) * FEAT + ks + col8 * 8];
        }
        #pragma unroll
        for (int kt = 0; kt < 128; kt += 32) {
            bf16x8 af = *(bf16x8*)&As[l16 * 136 + kt + quad * 8];
            #pragma unroll
            for (int n = 0; n < 2; n++) {
                bf16x8 bf = *(bf16x8*)&Bs[(n * 16 + l16) * 136 + kt + quad * 8];
                acc[n] = __builtin_amdgcn_mfma_f32_16x16x32_bf16(af, bf, acc[n], 0, 0, 0);
            }
        }
    }
    // cross-wave reduce of 4 K-quarter partials + fused column stats
    __syncthreads();                       // all waves done with own LDS
    float* sred = (float*)smem;            // [4][16][32]
    #pragma unroll
    for (int n = 0; n < 2; n++)
        #pragma unroll
        for (int e = 0; e < 4; e++)
            sred[(w * 16 + quad * 4 + e) * 32 + n * 16 + l16] = acc[n][e];
    __syncthreads();
    float* colS = sred + 2048;             // [8][32]
    float* colQ = colS + 256;              // [8][32]
    const int c  = tid & 31;
    const int r0 = tid >> 5;               // 0..7
    float v0 = 0.f, v1 = 0.f;
    #pragma unroll
    for (int ww = 0; ww < 4; ww++) {
        v0 += sred[(ww * 16 + r0) * 32 + c];
        v1 += sred[(ww * 16 + r0 + 8) * 32 + c];
    }
    X[(size_t)(mBase + r0) * HID + nBase + c]     = v0;
    X[(size_t)(mBase + r0 + 8) * HID + nBase + c] = v1;
    colS[r0 * 32 + c] = v0 + v1;
    colQ[r0 * 32 + c] = fmaf(v0, v0, v1 * v1);
    __syncthreads();
    if (tid < 32) {
        float s = 0.f, q = 0.f;
        #pragma unroll
        for (int r = 0; r < 8; r++) { s += colS[r * 32 + tid]; q += colQ[r * 32 + tid]; }
        statsP[blockIdx.y * 512 + nBase + tid]       = s;
        statsP[blockIdx.y * 512 + 256 + nBase + tid] = q;
    }
}

// ---- layer2 GEMM v2: 32x32 tiles, grid (8,32) = 256 blocks (full GPU).
// BN1 (aggregated from statsP) fused into A-staging; colstats2 partials
// plain-stored to stats2P[32][512]. No atomics anywhere.
__global__ __launch_bounds__(256) void gemm2_fused(
    const float* __restrict__ A /*x1*/, const ushort* __restrict__ B /*W2T*/,
    float* __restrict__ C /*x2*/, const float* __restrict__ statsP,
    const float* __restrict__ g1, const float* __restrict__ bt1,
    float* __restrict__ stats2P)
{
    __shared__ ushort As[32 * 72];
    __shared__ ushort Bs[32 * 72];
    __shared__ float sscale[HID];
    __shared__ float sshift[HID];
    __shared__ float csum[2][32];
    __shared__ float csq[2][32];
    const int tid  = threadIdx.x;
    const int lane = tid & 63;
    const int wave = tid >> 6;
    const int wy = wave >> 1, wx = wave & 1;
    const int quad = lane >> 4, l16 = lane & 15;
    const int mBase = blockIdx.y * 32;
    const int nBase = blockIdx.x * 32;

    {   // aggregate 64 row-partials -> BN1 scale/shift
        float s1 = 0.f, q1 = 0.f;
        #pragma unroll 8
        for (int y = 0; y < 64; y++) {
            s1 += statsP[y * 512 + tid];
            q1 += statsP[y * 512 + 256 + tid];
        }
        float m   = s1 * (1.f / 1024.f);
        float var = fmaf(-m, m, q1 * (1.f / 1024.f));
        float rstd = rsqrtf(var + 1e-5f);
        float sc = g1[tid] * rstd;
        sscale[tid] = sc;
        sshift[tid] = fmaf(-m, sc, bt1[tid]);
    }
    __syncthreads();

    f32x4 acc = {};
    for (int ks = 0; ks < HID; ks += 64) {
        #pragma unroll
        for (int p = 0; p < 2; p++) {      // A: 32x64 fp32, BN+ReLU+cvt
            const int c  = p * 256 + tid;
            const int r  = c >> 4;
            const int cq = c & 15;
            const int k0 = ks + cq * 4;
            float4 av = *(const float4*)&A[(size_t)(mBase + r) * HID + k0];
            float v0 = fmaxf(fmaf(sscale[k0 + 0], av.x, sshift[k0 + 0]), 0.f);
            float v1 = fmaxf(fmaf(sscale[k0 + 1], av.y, sshift[k0 + 1]), 0.f);
            float v2 = fmaxf(fmaf(sscale[k0 + 2], av.z, sshift[k0 + 2]), 0.f);
            float v3 = fmaxf(fmaf(sscale[k0 + 3], av.w, sshift[k0 + 3]), 0.f);
            ushort4 ao;
            ao.x = f2bf(v0); ao.y = f2bf(v1); ao.z = f2bf(v2); ao.w = f2bf(v3);
            *(ushort4*)&As[r * 72 + cq * 4] = ao;
        }
        {   // B: 32x64 bf16 copy, 1 chunk/thread
            const int row  = tid >> 3;
            const int col8 = tid & 7;
            *(bf16x8*)&Bs[row * 72 + col8 * 8] =
                *(const bf16x8*)&B[(size_t)(nBase + row) * HID + ks + col8 * 8];
        }
        __syncthreads();
        #pragma unroll
        for (int kt = 0; kt < 64; kt += 32) {
            bf16x8 af = *(bf16x8*)&As[(wy * 16 + l16) * 72 + kt + quad * 8];
            bf16x8 bf = *(bf16x8*)&Bs[(wx * 16 + l16) * 72 + kt + quad * 8];
            acc = __builtin_amdgcn_mfma_f32_16x16x32_bf16(af, bf, acc, 0, 0, 0);
        }
        __syncthreads();
    }

    float s = 0.f, q = 0.f;
    #pragma unroll
    for (int e = 0; e < 4; e++) {
        const int gm = mBase + wy * 16 + quad * 4 + e;
        const int gn = nBase + wx * 16 + l16;
        float v = acc[e];
        C[(size_t)gm * HID + gn] = v;
        s += v;
        q = fmaf(v, v, q);
    }
    s += __shfl_xor(s, 16, 64); s += __shfl_xor(s, 32, 64);
    q += __shfl_xor(q, 16, 64); q += __shfl_xor(q, 32, 64);
    if (quad == 0) {                       // unique (wy, wx*16+l16) per wave
        csum[wy][wx * 16 + l16] = s;
        csq [wy][wx * 16 + l16] = q;
    }
    __syncthreads();
    if (tid < 32) {
        stats2P[blockIdx.y * 512 + nBase + tid]       = csum[0][tid] + csum[1][tid];
        stats2P[blockIdx.y * 512 + 256 + nBase + tid] = csq[0][tid]  + csq[1][tid];
    }
}

// ---- dual edge GEMM, full K, plain stores; BN2 (from stats2P[32][512])
// ---- fused into A-staging. blockIdx.z = half. (x==0,half==0) emits di.
__global__ __launch_bounds__(256) void gemm_dual_bn(
    const float* __restrict__ A /*x2*/, const ushort* __restrict__ WeT,
    float* __restrict__ C1 /*hi*/, float* __restrict__ C2 /*hj*/,
    const float* __restrict__ stats2P,
    const float* __restrict__ g2, const float* __restrict__ bt2,
    float* __restrict__ di)
{
    __shared__ ushort As[64 * 72];
    __shared__ ushort Bs[64 * 72];
    __shared__ float sscale[HID];
    __shared__ float sshift[HID];
    const int tid  = threadIdx.x;
    const int lane = tid & 63;
    const int wave = tid >> 6;
    const int wy = wave >> 1, wx = wave & 1;
    const int quad = lane >> 4, l16 = lane & 15;
    const int mBase = blockIdx.y * 64;
    const int nBase = blockIdx.x * 64;
    const int half  = blockIdx.z;
    float* C = half ? C2 : C1;
    const bool writeDi = (blockIdx.x == 0) && (half == 0);

    {   // aggregate 32 row-partials -> BN2 scale/shift
        float s2 = 0.f, q2 = 0.f;
        #pragma unroll 8
        for (int y = 0; y < 32; y++) {
            s2 += stats2P[y * 512 + tid];
            q2 += stats2P[y * 512 + 256 + tid];
        }
        float m   = s2 * (1.f / 1024.f);
        float var = fmaf(-m, m, q2 * (1.f / 1024.f));
        float rstd = rsqrtf(var + 1e-5f);
        float sc = g2[tid] * rstd;
        sscale[tid] = sc;
        sshift[tid] = fmaf(-m, sc, bt2[tid]);
    }
    __syncthreads();

    f32x4 acc[2][2] = {};
    for (int ks = 0; ks < HID; ks += 64) {
        #pragma unroll
        for (int p = 0; p < 4; p++) {
            const int c  = p * 256 + tid;
            const int r  = c >> 4;
            const int cq = c & 15;
            const int k0 = ks + cq * 4;
            float4 av = *(const float4*)&A[(size_t)(mBase + r) * HID + k0];
            float v0 = fmaxf(fmaf(sscale[k0 + 0], av.x, sshift[k0 + 0]), 0.f);
            float v1 = fmaxf(fmaf(sscale[k0 + 1], av.y, sshift[k0 + 1]), 0.f);
            float v2 = fmaxf(fmaf(sscale[k0 + 2], av.z, sshift[k0 + 2]), 0.f);
            float v3 = fmaxf(fmaf(sscale[k0 + 3], av.w, sshift[k0 + 3]), 0.f);
            if (writeDi)
                *(float4*)&di[(size_t)(mBase + r) * HID + k0] =
                    make_float4(v0, v1, v2, v3);
            ushort4 ao;
            ao.x = f2bf(v0); ao.y = f2bf(v1); ao.z = f2bf(v2); ao.w = f2bf(v3);
            *(ushort4*)&As[r * 72 + cq * 4] = ao;
        }
        #pragma unroll
        for (int p = 0; p < 2; p++) {
            const int c    = p * 256 + tid;
            const int row  = c >> 3;
            const int col8 = c & 7;
            *(bf16x8*)&Bs[row * 72 + col8 * 8] =
                *(const bf16x8*)&WeT[(size_t)(nBase + row) * 512 + half * 256 + ks + col8 * 8];
        }
        __syncthreads();
        #pragma unroll
        for (int kt = 0; kt < 64; kt += 32) {
            bf16x8 af[2], bfr[2];
            #pragma unroll
            for (int mi = 0; mi < 2; mi++)
                af[mi] = *(bf16x8*)&As[(wy * 32 + mi * 16 + l16) * 72 + kt + quad * 8];
            #pragma unroll
            for (int ni = 0; ni < 2; ni++)
                bfr[ni] = *(bf16x8*)&Bs[(wx * 32 + ni * 16 + l16) * 72 + kt + quad * 8];
            #pragma unroll
            for (int mi = 0; mi < 2; mi++)
                #pragma unroll
                for (int ni = 0; ni < 2; ni++)
                    acc[mi][ni] = __builtin_amdgcn_mfma_f32_16x16x32_bf16(
                        af[mi], bfr[ni], acc[mi][ni], 0, 0, 0);
        }
        __syncthreads();
    }
    #pragma unroll
    for (int mi = 0; mi < 2; mi++)
        #pragma unroll
        for (int ni = 0; ni < 2; ni++)
            #pragma unroll
            for (int e = 0; e < 4; e++) {
                const int gm = mBase + wy * 32 + mi * 16 + quad * 4 + e;
                const int gn = nBase + wx * 32 + ni * 16 + l16;
                C[(size_t)gm * HID + gn] = acc[mi][ni][e];
            }
}

// ---------------- fused all-pairs edge network + node update ---------------
__global__ __launch_bounds__(256) void pair_update2(
    const float* __restrict__ di, const float* __restrict__ hi,
    const float* __restrict__ hj, const float* __restrict__ bwe1,
    const float* __restrict__ We2, const float* __restrict__ bwe2,
    const int* __restrict__ labels, float* __restrict__ out)
{
    __shared__ int   slab[N_PTS];
    __shared__ int   list[N_PTS];
    __shared__ int   cnt;
    __shared__ float sacc[16][HID];
    __shared__ float swsum[16];
    const int i   = blockIdx.x;
    const int tid = threadIdx.x;
    const int pid = tid >> 4;
    const int l16 = tid & 15;

    if (tid == 0) cnt = 0;
    for (int t = tid; t < N_PTS; t += 256) slab[t] = labels[t];
    __syncthreads();
    const int myLab = slab[i];
    for (int t = tid; t < N_PTS; t += 256)
        if (slab[t] == myLab && t != i) list[atomicAdd(&cnt, 1)] = t;
    __syncthreads();
    const int n = cnt;

    const float4* hip4 = (const float4*)(hi + (size_t)i * HID) + l16 * 4;
    const float4* bw4  = (const float4*)bwe1 + l16 * 4;
    const float4* w24  = (const float4*)We2  + l16 * 4;
    float4 hb[4], w2[4];
    #pragma unroll
    for (int s = 0; s < 4; s++) {
        float4 a = hip4[s], b = bw4[s];
        hb[s] = make_float4(a.x + b.x, a.y + b.y, a.z + b.z, a.w + b.w);
        w2[s] = w24[s];
    }
    const float b2 = bwe2[0];

    float4 acc[4] = {};
    float wloc = 0.f;
    const int rounds = (n + 15) >> 4;
    for (int r = 0; r < rounds; ++r) {
        const int idx = r * 16 + pid;
        const bool valid = idx < n;
        const int jj = valid ? list[idx] : i;
        const float4* hv4 = (const float4*)(hj + (size_t)jj * HID) + l16 * 4;
        float4 hv[4];
        #pragma unroll
        for (int s = 0; s < 4; s++) hv[s] = hv4[s];
        float p = 0.f;
        #pragma unroll
        for (int s = 0; s < 4; s++) {
            p = fmaf(fmaxf(hb[s].x + hv[s].x, 0.f), w2[s].x, p);
            p = fmaf(fmaxf(hb[s].y + hv[s].y, 0.f), w2[s].y, p);
            p = fmaf(fmaxf(hb[s].z + hv[s].z, 0.f), w2[s].z, p);
            p = fmaf(fmaxf(hb[s].w + hv[s].w, 0.f), w2[s].w, p);
        }
        p += __shfl_xor(p, 1, 64);
        p += __shfl_xor(p, 2, 64);
        p += __shfl_xor(p, 4, 64);
        p += __shfl_xor(p, 8, 64);
        const float w = valid ? 1.f / (1.f + expf(-(p + b2))) : 0.f;
        const float4* dv4 = (const float4*)(di + (size_t)jj * HID) + l16 * 4;
        #pragma unroll
        for (int s = 0; s < 4; s++) {
            float4 d = dv4[s];
            acc[s].x = fmaf(w, d.x, acc[s].x);
            acc[s].y = fmaf(w, d.y, acc[s].y);
            acc[s].z = fmaf(w, d.z, acc[s].z);
            acc[s].w = fmaf(w, d.w, acc[s].w);
        }
        if (l16 == 0) wloc += w;
    }
    #pragma unroll
    for (int s = 0; s < 4; s++)
        ((float4*)&sacc[pid][l16 * 16])[s] = acc[s];
    if (l16 == 0) swsum[pid] = wloc;
    __syncthreads();

    float at = 0.f;
    #pragma unroll
    for (int g = 0; g < 16; g++) at += sacc[g][tid];
    float wt = 0.f;
    #pragma unroll
    for (int g = 0; g < 16; g++) wt += swsum[g];
    const float dval = di[(size_t)i * HID + tid];
    out[(size_t)i * HID + tid] = dval + (wt > 0.f ? at / wt : 0.f);
}

extern "C" void kernel_launch(void* const* d_in, const int* in_sizes, int n_in,
                              void* d_out, int out_size, void* d_ws, size_t ws_size,
                              hipStream_t stream)
{
    const float* features = (const float*)d_in[0];
    const int*   labels   = (const int*)d_in[1];
    const float* W1   = (const float*)d_in[2];
    // b1/b2 cancel exactly through train-mode BN (mean subtraction)
    const float* g1   = (const float*)d_in[4];
    const float* bt1  = (const float*)d_in[5];
    const float* W2   = (const float*)d_in[6];
    const float* g2   = (const float*)d_in[8];
    const float* bt2  = (const float*)d_in[9];
    const float* We1  = (const float*)d_in[10];
    const float* bwe1 = (const float*)d_in[11];
    const float* We2  = (const float*)d_in[12];
    const float* bwe2 = (const float*)d_in[13];
    float* out = (float*)d_out;

    float* ws      = (float*)d_ws;
    float* x1      = ws;               // 262144 (plain stores)
    float* hi      = ws + 262144;      // 262144 (plain stores)
    float* hj      = ws + 524288;      // 262144 (plain stores)
    float* x2      = ws + 786432;      // 262144 (plain stores)
    float* di      = ws + 1048576;     // 262144 (plain stores)
    float* statsP  = ws + 1310720;     // [64][512] col-stat partials (plain)
    float* stats2P = ws + 1343488;     // [32][512] col-stat partials (plain)
    ushort* W1T  = (ushort*)(ws + 1359872);   // 256*2048 bf16
    ushort* W2T  = W1T + 524288;              // 256*256 bf16
    ushort* WeT  = W2T + 65536;               // 256*512 bf16

    dim3 blk(256);
    // weight pre-transposes only (feature conversion fused into gemm1s)
    prep<<<176, blk, 0, stream>>>(W1, W2, We1, W1T, W2T, WeT);
    // layer 1: wave-split-K full-K GEMM, fused colstats1 partials
    gemm1s<<<dim3(8, 64), blk, 0, stream>>>(features, W1T, x1, statsP);
    // layer 2: 32x32 tiles, full GPU; BN1 in preamble, colstats2 in epilogue
    gemm2_fused<<<dim3(8, 32), blk, 0, stream>>>(x1, W2T, x2, statsP,
                                                 g1, bt1, stats2P);
    // edge net halves + BN2/ReLU fused into A-staging; emits di
    gemm_dual_bn<<<dim3(4, 16, 2), blk, 0, stream>>>(x2, WeT, hi, hj,
                                                     stats2P, g2, bt2, di);
    // fused all-pairs edge weights + node feature update
    pair_update2<<<N_PTS, blk, 0, stream>>>(di, hi, hj, bwe1, We2, bwe2,
                                            labels, out);
}